// Round 2
// baseline (82451.324 us; speedup 1.0000x reference)
//
#include <hip/hip_runtime.h>
#include <math.h>

// LTC liquid-cell scan, S=2 neuron-split.
// 128 batches x 2 slices = 256 blocks (1 per CU). Each block owns 256 neurons,
// streams only its 0.5 MB half of W_rec^T per unfold (the per-CU L2 path is the
// roofline: 1536 sequential unfolds x bytes/CU / ~144 GB/s). Partner x-halves
// are exchanged per unfold through a double-buffered global mailbox with
// agent-scope atomics; the own-k half of the GEMV runs before the spin-wait so
// cross-XCD latency is hidden. fp32 throughout (bf16 W fails numerics: ~0.2%
// coherent perturbation amplified ~5e3x through the pre-saturation transient).

#define NN 512
#define HN 256   // neurons per block (S=2)
#define FF 256
#define KK 6
#define BB 128
#define TT 256

__global__ void transpose_k(const float* __restrict__ W, float* __restrict__ WT,
                            int rows, int cols) {
  // W is [rows][cols], WT is [cols][rows]
  __shared__ float tile[32][33];
  const int c0 = blockIdx.x * 32;
  const int r0 = blockIdx.y * 32;
  for (int j = threadIdx.y; j < 32; j += 8)
    tile[j][threadIdx.x] = W[(size_t)(r0 + j) * cols + (c0 + threadIdx.x)];
  __syncthreads();
  for (int j = threadIdx.y; j < 32; j += 8)
    WT[(size_t)(c0 + j) * rows + (r0 + threadIdx.x)] = tile[threadIdx.x][j];
}

__global__ void init_flags(int* flg) { flg[threadIdx.x] = 0; }

#define GEMV_QUARTER(WBASE, XBASE)                                         \
  {                                                                        \
    const float*  wp = (WBASE);                                            \
    const float4* xp = (const float4*)(XBASE);                             \
    _Pragma("unroll")                                                      \
    for (int q = 0; q < 4; ++q) {                                          \
      float4 xv = xp[q];                                                   \
      float4 w0 = *(const float4*)(wp + (size_t)(4 * q + 0) * NN);         \
      float4 w1 = *(const float4*)(wp + (size_t)(4 * q + 1) * NN);         \
      float4 w2 = *(const float4*)(wp + (size_t)(4 * q + 2) * NN);         \
      float4 w3 = *(const float4*)(wp + (size_t)(4 * q + 3) * NN);         \
      ax += w0.x * xv.x + w1.x * xv.y + w2.x * xv.z + w3.x * xv.w;         \
      ay += w0.y * xv.x + w1.y * xv.y + w2.y * xv.z + w3.y * xv.w;         \
      az += w0.z * xv.x + w1.z * xv.y + w2.z * xv.z + w3.z * xv.w;         \
      aw += w0.w * xv.x + w1.w * xv.y + w2.w * xv.z + w3.w * xv.w;         \
    }                                                                      \
  }

__global__ __launch_bounds__(1024) void liquid_kernel(
    const float* __restrict__ I,     // [B][T][F]
    const float* __restrict__ DT,    // [B][T]
    const float* __restrict__ WrT,   // [N][N]  WrT[k][n] = W_rec[n][k]
    const float* __restrict__ WiT,   // [F][N]  WiT[f][n] = W_in[n][f]
    const float* __restrict__ bv,
    const float* __restrict__ Av,
    const float* __restrict__ tauv,
    float* __restrict__ xmb,         // mailbox [B][2 writer][2 slot][HN]
    int* __restrict__ flg,           // [B][2]
    float* __restrict__ out)         // [B][T][N]
{
  __shared__ float xs[NN];           // full recurrent state (own half + staged partner half)
  __shared__ float irow[FF];
  __shared__ float partial[16][HN];  // 16 k-group partials (16 KB)

  const int blk = blockIdx.x;
  const int b   = blk >> 1;          // batch
  const int s   = blk & 1;           // neuron slice
  const int tid = threadIdx.x;
  const int g   = tid >> 6;          // k-group 0..15 (== wave id)
  const int c   = tid & 63;          // owns outputs 4c..4c+3 of this slice

  float rA = 0.f, rInvTau = 0.f, rB = 0.f;
  if (tid < HN) {
    const int n = s * HN + tid;
    rA      = Av[n];
    rInvTau = 1.0f / tauv[n];
    rB      = bv[n];
  }
  if (tid < NN) xs[tid] = 0.0f;      // x0 = tanh(0) = 0 (both halves)

  const float* Ib   = I   + (size_t)b * TT * FF;
  float*       outb = out + (size_t)b * TT * NN;
  float*       mb_out = xmb + (size_t)((b * 2 + s) * 2) * HN;
  const float* mb_in  = xmb + (size_t)((b * 2 + (1 - s)) * 2) * HN;
  int* ownflag = flg + (b * 2 + s);
  int* pflag   = flg + (b * 2 + (1 - s));

  __syncthreads();

  int jj = 0;                        // global unfold counter (published x index)
  for (int t = 0; t < TT; ++t) {
    if (tid < FF) irow[tid] = Ib[(size_t)t * FF + tid];
    const float dtk = DT[(size_t)b * TT + t] * (1.0f / KK);
    __syncthreads();

    // ---- inp = i_t @ W_in^T (own 256 cols): 16 k-groups x 16 k ----
    {
      float ax = 0.f, ay = 0.f, az = 0.f, aw = 0.f;
      GEMV_QUARTER(WiT + (size_t)(g * 16) * NN + s * HN + 4 * c, irow + g * 16);
      *(float4*)&partial[g][4 * c] = make_float4(ax, ay, az, aw);
    }
    __syncthreads();
    float rInp = 0.f;
    if (tid < HN) {
      float ss = rB;
      #pragma unroll
      for (int gg = 0; gg < 16; ++gg) ss += partial[gg][tid];
      rInp = ss;
    }
    __syncthreads();   // partial[] free for reuse by unfold 0

    // ---- K semi-implicit unfolds ----
    float xcur = 0.f;
    #pragma unroll 1
    for (int kk = 0; kk < KK; ++kk) {
      ++jj;                                    // this unfold produces x_jj
      float ax = 0.f, ay = 0.f, az = 0.f, aw = 0.f;

      // own-k half first (x available locally) — hides exchange latency
      {
        const int k0 = s * HN + g * 16;
        GEMV_QUARTER(WrT + (size_t)k0 * NN + s * HN + 4 * c, xs + k0);
      }
      // stage partner's x_{jj-1} (slot (jj-1)&1); jj==1 reads nothing (x0=0)
      if (jj > 1 && tid < HN) {
        while (__hip_atomic_load(pflag, __ATOMIC_ACQUIRE,
                                 __HIP_MEMORY_SCOPE_AGENT) < jj - 1)
          __builtin_amdgcn_s_sleep(1);
        float v = __hip_atomic_load(mb_in + ((jj - 1) & 1) * HN + tid,
                                    __ATOMIC_RELAXED, __HIP_MEMORY_SCOPE_AGENT);
        xs[(1 - s) * HN + tid] = v;            // disjoint from own-half reads
      }
      __syncthreads();

      // partner-k half
      {
        const int k0 = (1 - s) * HN + g * 16;
        GEMV_QUARTER(WrT + (size_t)k0 * NN + s * HN + 4 * c, xs + k0);
      }
      *(float4*)&partial[g][4 * c] = make_float4(ax, ay, az, aw);
      __syncthreads();

      if (tid < HN) {
        float arg = rInp;
        #pragma unroll
        for (int gg = 0; gg < 16; ++gg) arg += partial[gg][tid];
        float f  = tanhf(arg);
        float xo = xs[s * HN + tid];
        float xn = fmaf(dtk * f, rA, xo) / fmaf(dtk, rInvTau + f, 1.0f);
        xs[s * HN + tid] = xn;
        xcur = xn;
        // publish x_jj into slot jj&1 (partner consumed our x_{jj-2} already:
        // we observed pflag >= jj-1 above, which implies it)
        __hip_atomic_store(mb_out + (jj & 1) * HN + tid, xn,
                           __ATOMIC_RELAXED, __HIP_MEMORY_SCOPE_AGENT);
        __threadfence();                       // data visible before flag
      }
      __syncthreads();                         // all fences done before release
      if (tid == 0)
        __hip_atomic_store(ownflag, jj, __ATOMIC_RELEASE,
                           __HIP_MEMORY_SCOPE_AGENT);
    }
    if (tid < HN) outb[(size_t)t * NN + s * HN + tid] = xcur;
  }
}

extern "C" void kernel_launch(void* const* d_in, const int* in_sizes, int n_in,
                              void* d_out, int out_size, void* d_ws, size_t ws_size,
                              hipStream_t stream) {
  const float* I    = (const float*)d_in[0];
  const float* DT   = (const float*)d_in[1];
  const float* Wrec = (const float*)d_in[2];  // [N][N]
  const float* Win  = (const float*)d_in[3];  // [N][F]
  const float* bv   = (const float*)d_in[4];
  const float* Av   = (const float*)d_in[5];
  const float* tauv = (const float*)d_in[6];
  float* out = (float*)d_out;

  float* WrT = (float*)d_ws;                  // 512*512 f = 1 MB
  float* WiT = WrT + NN * NN;                 // 256*512 f = 0.5 MB
  float* xmb = WiT + FF * NN;                 // 128*2*2*256 f = 1 MB
  int*   flg = (int*)(xmb + BB * 2 * 2 * HN); // 256 ints

  dim3 tb(32, 8);
  transpose_k<<<dim3(NN / 32, NN / 32), tb, 0, stream>>>(Wrec, WrT, NN, NN);
  transpose_k<<<dim3(FF / 32, NN / 32), tb, 0, stream>>>(Win,  WiT, NN, FF);
  init_flags<<<1, 2 * BB, 0, stream>>>(flg);
  liquid_kernel<<<2 * BB, 1024, 0, stream>>>(I, DT, WrT, WiT, bv, Av, tauv,
                                             xmb, flg, out);
}

// Round 3
// 14436.337 us; speedup vs baseline: 5.7114x; 5.7114x over previous
//
#include <hip/hip_runtime.h>
#include <math.h>

typedef unsigned long long ull;

// LTC liquid scan, S=2 neuron split, W_rec held IN-CORE.
// 256 blocks x 512 threads, 1 block/CU (96 KB LDS + ~250 VGPR force spread).
// Per block: 256 output neurons, W slice 512 KB = 192 f32/thread in VGPR
// (wv[6][8] float4) + 32 f32/thread in LDS (j=7, stride-36 pad) + 32 f32/thread
// (j=6) re-read per unfold from a 128 KB packed L2-resident buffer.
// Cross-block x exchange: fence-free versioned 8-byte mailbox slots, RELAXED
// agent-scope atomics only (round-2 lesson: acquire fences emit cache
// invalidates -> 50 GB HBM refetch storm). Two slots (jj parity) prevent
// overwrite-before-consume. Partner = blk^8 (same XCD under %8 dispatch).

#define NN 512
#define HN 256
#define FF 256
#define KK 6
#define BB 128
#define TT 256
#define NT 512

__global__ void transpose_k(const float* __restrict__ W, float* __restrict__ WT,
                            int rows, int cols) {
  __shared__ float tile[32][33];
  const int c0 = blockIdx.x * 32;
  const int r0 = blockIdx.y * 32;
  for (int j = threadIdx.y; j < 32; j += 8)
    tile[j][threadIdx.x] = W[(size_t)(r0 + j) * cols + (c0 + threadIdx.x)];
  __syncthreads();
  for (int j = threadIdx.y; j < 32; j += 8)
    WT[(size_t)(c0 + j) * rows + (r0 + threadIdx.x)] = tile[threadIdx.x][j];
}

// pack j=6 chunk (k in [384,448)): pw[(s*8+u)*512 + t] =
//   W_rec[s*256 + (t>>4)*8 + u][4*(t&15) + 384 .. +3]
__global__ void pack_w(const float* __restrict__ Wrec, float4* __restrict__ pw) {
  const int idx = blockIdx.x * 256 + threadIdx.x;   // 0..8191
  const int t = idx & 511, u = (idx >> 9) & 7, s = idx >> 12;
  const int neuron = s * HN + ((t >> 4) << 3) + u;
  pw[idx] = *(const float4*)&Wrec[(size_t)neuron * NN + 4 * (t & 15) + 384];
}

__global__ __launch_bounds__(NT, 2) void liquid_kernel(
    const float* __restrict__ I, const float* __restrict__ DT,
    const float* __restrict__ Wrec, const float* __restrict__ WiT,
    const float4* __restrict__ pw, const float* __restrict__ bv,
    const float* __restrict__ Av, const float* __restrict__ tauv,
    ull* __restrict__ mb, float* __restrict__ out) {
  __shared__ float lds[24576];            // 96 KB -> 1 block/CU guaranteed
  float* xs       = lds;                  // [512]
  float* irow     = lds + 512;            // [256]
  float* partials = lds + 768;            // [256][17] = 4352 (stride-17 pad)
  float* Wlds     = lds + 5120;           // [512][36] = 18432 (j=7 chunk)

  const int blk = blockIdx.x;
  const int s   = (blk >> 3) & 1;                 // slice
  const int b   = (blk & 7) | ((blk >> 4) << 3);  // batch; partner = blk^8
  const int tid = threadIdx.x;
  const int kc  = tid & 15;               // k-chunk 0..15
  const int n0  = (tid >> 4) << 3;        // local neuron base (8 per thread)

  // ---- W slice into VGPRs (j=0..5) and LDS (j=7) ----
  float4 wv[6][8];
  #pragma unroll
  for (int j = 0; j < 6; ++j)
    #pragma unroll
    for (int u = 0; u < 8; ++u)
      wv[j][u] = *(const float4*)&Wrec[(size_t)(s * HN + n0 + u) * NN + 4 * kc + 64 * j];
  #pragma unroll
  for (int u = 0; u < 8; ++u)
    *(float4*)&Wlds[tid * 36 + 4 * u] =
        *(const float4*)&Wrec[(size_t)(s * HN + n0 + u) * NN + 4 * kc + 448];

  float rA = 0.f, rIT = 0.f, rB = 0.f;
  if (tid < HN) {
    rA = Av[s * HN + tid];
    rIT = 1.0f / tauv[s * HN + tid];
    rB = bv[s * HN + tid];
  }
  xs[tid] = 0.f;                           // x0 = tanh(0) = 0 (all 512)

  const float* Ib   = I + (size_t)b * TT * FF;
  float*       outb = out + (size_t)b * TT * NN;
  ull*       mb_out = mb + (size_t)((b * 2 + s) * 2) * HN;
  const ull* mb_in  = mb + (size_t)((b * 2 + (1 - s)) * 2) * HN;

  const int q = tid & 63;                  // input GEMV n-quad
  const int h = tid >> 6;                  // input GEMV k-octant (wave-uniform)

  __syncthreads();

  int jj = 0;
  float xcur = 0.f;
  #pragma unroll 1
  for (int t = 0; t < TT; ++t) {
    if (tid < FF) irow[tid] = Ib[(size_t)t * FF + tid];
    const float dtk = DT[(size_t)b * TT + t] * (1.0f / KK);
    __syncthreads();

    // ---- input GEMV: inp[4q+e] partial over k in [32h, 32h+32) ----
    {
      float ax = 0.f, ay = 0.f, az = 0.f, aw = 0.f;
      #pragma unroll
      for (int m4 = 0; m4 < 8; ++m4) {
        float4 iv = *(const float4*)&irow[h * 32 + 4 * m4];
        const float* wk = &WiT[(size_t)(h * 32 + 4 * m4) * NN + s * HN + 4 * q];
        float4 w0 = *(const float4*)(wk + 0 * NN);
        float4 w1 = *(const float4*)(wk + 1 * NN);
        float4 w2 = *(const float4*)(wk + 2 * NN);
        float4 w3 = *(const float4*)(wk + 3 * NN);
        ax += w0.x * iv.x + w1.x * iv.y + w2.x * iv.z + w3.x * iv.w;
        ay += w0.y * iv.x + w1.y * iv.y + w2.y * iv.z + w3.y * iv.w;
        az += w0.z * iv.x + w1.z * iv.y + w2.z * iv.z + w3.z * iv.w;
        aw += w0.w * iv.x + w1.w * iv.y + w2.w * iv.z + w3.w * iv.w;
      }
      partials[(4 * q + 0) * 17 + h] = ax;
      partials[(4 * q + 1) * 17 + h] = ay;
      partials[(4 * q + 2) * 17 + h] = az;
      partials[(4 * q + 3) * 17 + h] = aw;
    }
    __syncthreads();
    float rInp = 0.f;
    if (tid < HN) {
      float ssum = rB;
      #pragma unroll
      for (int hh = 0; hh < 8; ++hh) ssum += partials[tid * 17 + hh];
      rInp = ssum;
    }
    __syncthreads();

    // ---- K semi-implicit unfolds ----
    #pragma unroll 1
    for (int kk = 0; kk < KK; ++kk) {
      ++jj;                                // producing x_jj
      float acc[8] = {0.f, 0.f, 0.f, 0.f, 0.f, 0.f, 0.f, 0.f};

      // j=6 chunk from L2 (anti-hoist: keep these as per-unfold reloads so
      // they don't become 32 permanently-resident VGPRs and blow the budget)
      const float4* pwp = pw;
      asm volatile("" : "+v"(pwp));
      float4 wl[8];
      #pragma unroll
      for (int u = 0; u < 8; ++u) wl[u] = pwp[(size_t)(s * 8 + u) * 512 + tid];

#define FMA_J(j)                                                               \
  {                                                                            \
    float4 xv = *(const float4*)&xs[4 * kc + 64 * (j)];                        \
    _Pragma("unroll") for (int u = 0; u < 8; ++u) {                            \
      acc[u] += wv[j][u].x * xv.x + wv[j][u].y * xv.y + wv[j][u].z * xv.z +    \
                wv[j][u].w * xv.w;                                             \
    }                                                                          \
  }
#define FMA_WL()                                                               \
  {                                                                            \
    float4 xv = *(const float4*)&xs[4 * kc + 384];                             \
    _Pragma("unroll") for (int u = 0; u < 8; ++u) {                            \
      acc[u] += wl[u].x * xv.x + wl[u].y * xv.y + wl[u].z * xv.z +             \
                wl[u].w * xv.w;                                                \
    }                                                                          \
  }
#define FMA_LD()                                                               \
  {                                                                            \
    float4 xv = *(const float4*)&xs[4 * kc + 448];                             \
    _Pragma("unroll") for (int u = 0; u < 8; ++u) {                            \
      float4 wq = *(const float4*)&Wlds[tid * 36 + 4 * u];                     \
      acc[u] += wq.x * xv.x + wq.y * xv.y + wq.z * xv.z + wq.w * xv.w;         \
    }                                                                          \
  }

      // own-half FMAs (x locally available from last unfold)
      if (s == 0) { FMA_J(0) FMA_J(1) FMA_J(2) FMA_J(3) }
      else        { FMA_J(4) FMA_J(5) FMA_WL() FMA_LD() }

      // stage partner x_{jj-1}: versioned slot, RELAXED only (no fences!)
      if (jj > 1 && tid < HN) {
        const ull* slot = mb_in + ((jj - 1) & 1) * HN + tid;
        ull v;
        for (;;) {
          v = __hip_atomic_load(slot, __ATOMIC_RELAXED, __HIP_MEMORY_SCOPE_AGENT);
          if ((unsigned)(v >> 32) == (unsigned)(jj - 1)) break;
          __builtin_amdgcn_s_sleep(2);
        }
        xs[(1 - s) * HN + tid] = __uint_as_float((unsigned)v);
      }
      __syncthreads();

      // partner-half FMAs
      if (s == 0) { FMA_J(4) FMA_J(5) FMA_WL() FMA_LD() }
      else        { FMA_J(0) FMA_J(1) FMA_J(2) FMA_J(3) }

      #pragma unroll
      for (int u = 0; u < 8; ++u) partials[(n0 + u) * 17 + kc] = acc[u];
      __syncthreads();

      if (tid < HN) {
        float arg = rInp;
        #pragma unroll
        for (int c = 0; c < 16; ++c) arg += partials[tid * 17 + c];
        float f  = tanhf(arg);
        float xo = xs[s * HN + tid];
        float xn = fmaf(dtk * f, rA, xo) / fmaf(dtk, rIT + f, 1.0f);
        xs[s * HN + tid] = xn;
        xcur = xn;
        // publish x_jj (value+version in one word: indivisible, fence-free)
        __hip_atomic_store(mb_out + (jj & 1) * HN + tid,
                           ((ull)(unsigned)jj << 32) | __float_as_uint(xn),
                           __ATOMIC_RELAXED, __HIP_MEMORY_SCOPE_AGENT);
      }
      __syncthreads();
    }
    if (tid < HN) outb[(size_t)t * NN + s * HN + tid] = xcur;
  }
}

extern "C" void kernel_launch(void* const* d_in, const int* in_sizes, int n_in,
                              void* d_out, int out_size, void* d_ws, size_t ws_size,
                              hipStream_t stream) {
  const float* I    = (const float*)d_in[0];
  const float* DT   = (const float*)d_in[1];
  const float* Wrec = (const float*)d_in[2];  // [N][N]
  const float* Win  = (const float*)d_in[3];  // [N][F]
  const float* bv   = (const float*)d_in[4];
  const float* Av   = (const float*)d_in[5];
  const float* tauv = (const float*)d_in[6];
  float* out = (float*)d_out;

  float*  WiT = (float*)d_ws;                      // [256][512] = 512 KB
  float4* pw  = (float4*)(WiT + FF * NN);          // 8192 float4 = 128 KB
  ull*    mb  = (ull*)((char*)d_ws + (512 + 128) * 1024);  // [128][2][2][256] = 1 MB

  dim3 tb(32, 8);
  transpose_k<<<dim3(FF / 32, NN / 32), tb, 0, stream>>>(Win, WiT, NN, FF);
  pack_w<<<32, 256, 0, stream>>>(Wrec, pw);
  liquid_kernel<<<2 * BB, NT, 0, stream>>>(I, DT, Wrec, WiT, pw, bv, Av, tauv,
                                           mb, out);
}

// Round 4
// 8715.422 us; speedup vs baseline: 9.4604x; 1.6564x over previous
//
#include <hip/hip_runtime.h>
#include <math.h>

typedef unsigned long long ull;

// LTC liquid scan — batch-amortized GEMM decomposition.
// Grid 256 = 16 batch-tiles x 16 neuron-tiles; block 512 threads, 1 block/CU
// (84 KB LDS forces it; co-residency => spin-wait is safe).
// Each block's W_rec slice [32 n][512 k] = 64 KB lives in VGPRs (128/thread,
// loaded ONCE for all 1536 unfolds — round-3 spill lesson: keep <=128 regs).
// W_in slice [32 n][256 f] = 32 KB lives in LDS. Per-unfold cross-block state
// exchange x[8][512] via fence-free versioned 8-byte mailbox (RELAXED agent
// atomics only — round-2 lesson: acquire fences => cache-invalidate storm).
// 2 slots (jj parity); 16-way induction: publishing x_jj requires having
// consumed all peers' x_{jj-1}, which requires peers consumed our x_{jj-2},
// so overwriting slot jj&1 is safe. Poison 0xAA.. never matches a version.

#define NN 512
#define FF 256
#define KK 6
#define BB 128
#define TT 256
#define BT 8         // batches per tile
#define NTL 32       // neurons per tile

#define XPITCH 516   // x row pad (bank stagger)
#define IPITCH 260
#define WIPITCH 260
#define PPITCH 17

#define DOT4(a, v) ((a).x * (v).x + (a).y * (v).y + (a).z * (v).z + (a).w * (v).w)

__global__ __launch_bounds__(512, 2) void liquid_kernel(
    const float* __restrict__ I,     // [B][T][F]
    const float* __restrict__ DT,    // [B][T]
    const float* __restrict__ Wrec,  // [N][N]
    const float* __restrict__ Win,   // [N][F]
    const float* __restrict__ bv, const float* __restrict__ Av,
    const float* __restrict__ tauv,
    ull* __restrict__ mbx,           // [16 bt][2 slot][8 b][512 n] versioned
    float* __restrict__ out)         // [B][T][N]
{
  __shared__ float lds[21504];       // 84 KB -> 1 block/CU
  float* xsh = lds;                  // [8][516]  x_{jj-1}, global-n indexed
  float* iro = lds + 8 * XPITCH;     // [8][260]  input rows
  float* wi  = iro + 8 * IPITCH;     // [32][260] W_in slice
  float* par = wi + NTL * WIPITCH;   // [256][17] k-chunk partials
  float* dts = par + 256 * PPITCH;   // [8] dt/K per batch

  const int blk = blockIdx.x;
  const int bt  = blk >> 4;          // batch tile
  const int nt  = blk & 15;          // neuron tile
  const int tid = threadIdx.x;
  const int kc  = tid & 15;          // k-chunk (32 k each)
  const int nq  = (tid >> 4) & 7;    // n-quad (4 n each)
  const int db  = tid >> 7;          // b-pair (2 b each)
  const int n0g = nt * NTL;          // global n base of this tile

  // ---- W_rec slice into VGPRs: wv[r][j] = Wrec[n0g+4nq+r][32kc+4j .. +3] ----
  float4 wv[4][8];
  #pragma unroll
  for (int r = 0; r < 4; ++r) {
    const float* wr = Wrec + (size_t)(n0g + nq * 4 + r) * NN + kc * 32;
    #pragma unroll
    for (int j = 0; j < 8; ++j) wv[r][j] = *(const float4*)(wr + 4 * j);
  }
  // ---- W_in slice into LDS ----
  for (int idx = tid; idx < NTL * FF; idx += 512) {
    const int n = idx >> 8, f = idx & 255;
    wi[n * WIPITCH + f] = Win[(size_t)(n0g + n) * FF + f];
  }
  // ---- per-neuron params for reduction threads (tid<256: b=tid>>5,n=tid&31) ----
  float rA = 0.f, rIT = 0.f, rB = 0.f;
  if (tid < 256) {
    const int n = n0g + (tid & 31);
    rA = Av[n]; rIT = 1.0f / tauv[n]; rB = bv[n];
  }
  for (int idx = tid; idx < BT * XPITCH; idx += 512) xsh[idx] = 0.f;  // x0=0
  __syncthreads();

  int jj = 0;
  #pragma unroll 1
  for (int t = 0; t < TT; ++t) {
    // ---- stage input rows + dt ----
    {
      const int b = tid >> 6, f0 = (tid & 63) * 4;
      *(float4*)&iro[b * IPITCH + f0] =
          *(const float4*)&I[((size_t)(bt * BT + b) * TT + t) * FF + f0];
      if (tid < BT) dts[tid] = DT[(size_t)(bt * BT + tid) * TT + t] * (1.0f / KK);
    }
    __syncthreads();

    // ---- input GEMV partials: inp[b][n] over f in [16kc,16kc+16) ----
    {
      float ai0[4] = {0.f, 0.f, 0.f, 0.f}, ai1[4] = {0.f, 0.f, 0.f, 0.f};
      const float* wbase = wi + (nq * 4) * WIPITCH + kc * 16;
      const float* i0 = iro + (db * 2 + 0) * IPITCH + kc * 16;
      const float* i1 = iro + (db * 2 + 1) * IPITCH + kc * 16;
      #pragma unroll
      for (int j2 = 0; j2 < 4; ++j2) {
        float4 w0 = *(const float4*)(wbase + 0 * WIPITCH + 4 * j2);
        float4 w1 = *(const float4*)(wbase + 1 * WIPITCH + 4 * j2);
        float4 w2 = *(const float4*)(wbase + 2 * WIPITCH + 4 * j2);
        float4 w3 = *(const float4*)(wbase + 3 * WIPITCH + 4 * j2);
        float4 xa = *(const float4*)(i0 + 4 * j2);
        float4 xb = *(const float4*)(i1 + 4 * j2);
        ai0[0] += DOT4(w0, xa); ai0[1] += DOT4(w1, xa);
        ai0[2] += DOT4(w2, xa); ai0[3] += DOT4(w3, xa);
        ai1[0] += DOT4(w0, xb); ai1[1] += DOT4(w1, xb);
        ai1[2] += DOT4(w2, xb); ai1[3] += DOT4(w3, xb);
      }
      #pragma unroll
      for (int r = 0; r < 4; ++r) {
        par[((db * 2 + 0) * NTL + nq * 4 + r) * PPITCH + kc] = ai0[r];
        par[((db * 2 + 1) * NTL + nq * 4 + r) * PPITCH + kc] = ai1[r];
      }
    }
    __syncthreads();
    float rInp = 0.f;
    if (tid < 256) {
      float s = rB;
      #pragma unroll
      for (int c = 0; c < 16; ++c) s += par[tid * PPITCH + c];
      rInp = s;
    }
    __syncthreads();  // par free for unfold reuse

    // ---- K unfolds ----
    #pragma unroll 1
    for (int kk = 0; kk < KK; ++kk) {
      ++jj;  // producing x_jj; consuming x_{jj-1}

      // stage x_{jj-1}[8][512] from mailbox (skip jj==1: x0=0 already in xsh)
      if (jj > 1) {
        const ull* src = mbx + (((size_t)bt * 2 + ((jj - 1) & 1)) << 12);
        const int sb = tid >> 6, sn = (tid & 63) * 8;
        const ull* p = src + sb * 512 + sn;
        ull v[8];
        #pragma unroll
        for (int i = 0; i < 8; ++i)
          v[i] = __hip_atomic_load(p + i, __ATOMIC_RELAXED, __HIP_MEMORY_SCOPE_AGENT);
        #pragma unroll
        for (int i = 0; i < 8; ++i)
          while ((unsigned)(v[i] >> 32) != (unsigned)(jj - 1)) {
            __builtin_amdgcn_s_sleep(1);
            v[i] = __hip_atomic_load(p + i, __ATOMIC_RELAXED, __HIP_MEMORY_SCOPE_AGENT);
          }
        float* xrow = xsh + sb * XPITCH + sn;
        #pragma unroll
        for (int i = 0; i < 8; ++i) xrow[i] = __uint_as_float((unsigned)v[i]);
      }
      __syncthreads();

      // GEMV: acc[b][n] partial over k in [32kc, 32kc+32), W from VGPRs
      {
        float acc0[4] = {0.f, 0.f, 0.f, 0.f}, acc1[4] = {0.f, 0.f, 0.f, 0.f};
        const float* xb0 = xsh + (db * 2 + 0) * XPITCH + kc * 32;
        const float* xb1 = xsh + (db * 2 + 1) * XPITCH + kc * 32;
        #pragma unroll
        for (int j = 0; j < 8; ++j) {
          float4 xv = *(const float4*)(xb0 + 4 * j);
          acc0[0] += DOT4(wv[0][j], xv); acc0[1] += DOT4(wv[1][j], xv);
          acc0[2] += DOT4(wv[2][j], xv); acc0[3] += DOT4(wv[3][j], xv);
        }
        #pragma unroll
        for (int j = 0; j < 8; ++j) {
          float4 xv = *(const float4*)(xb1 + 4 * j);
          acc1[0] += DOT4(wv[0][j], xv); acc1[1] += DOT4(wv[1][j], xv);
          acc1[2] += DOT4(wv[2][j], xv); acc1[3] += DOT4(wv[3][j], xv);
        }
        #pragma unroll
        for (int r = 0; r < 4; ++r) {
          par[((db * 2 + 0) * NTL + nq * 4 + r) * PPITCH + kc] = acc0[r];
          par[((db * 2 + 1) * NTL + nq * 4 + r) * PPITCH + kc] = acc1[r];
        }
      }
      __syncthreads();

      // reduce + nonlinearity + publish (+ output on last unfold)
      if (tid < 256) {
        float arg = rInp;
        #pragma unroll
        for (int c = 0; c < 16; ++c) arg += par[tid * PPITCH + c];
        const int rb = tid >> 5, rn = tid & 31;
        float f   = tanhf(arg);
        float dtk = dts[rb];
        float xo  = xsh[rb * XPITCH + n0g + rn];
        float xn  = fmaf(dtk * f, rA, xo) / fmaf(dtk, rIT + f, 1.0f);
        ull w = ((ull)(unsigned)jj << 32) | (ull)__float_as_uint(xn);
        __hip_atomic_store(mbx + (((size_t)bt * 2 + (jj & 1)) << 12) + rb * 512 + n0g + rn,
                           w, __ATOMIC_RELAXED, __HIP_MEMORY_SCOPE_AGENT);
        if (kk == KK - 1)
          out[((size_t)(bt * BT + rb) * TT + t) * NN + n0g + rn] = xn;
      }
      __syncthreads();  // xsh/par reads done before next stage overwrites
    }
  }
}

extern "C" void kernel_launch(void* const* d_in, const int* in_sizes, int n_in,
                              void* d_out, int out_size, void* d_ws, size_t ws_size,
                              hipStream_t stream) {
  const float* I    = (const float*)d_in[0];
  const float* DT   = (const float*)d_in[1];
  const float* Wrec = (const float*)d_in[2];
  const float* Win  = (const float*)d_in[3];
  const float* bv   = (const float*)d_in[4];
  const float* Av   = (const float*)d_in[5];
  const float* tauv = (const float*)d_in[6];
  float* out = (float*)d_out;
  ull* mbx = (ull*)d_ws;  // 16*2*8*512*8 B = 1 MB

  liquid_kernel<<<256, 512, 0, stream>>>(I, DT, Wrec, Win, bv, Av, tauv, mbx, out);
}